// Round 10
// baseline (245.101 us; speedup 1.0000x reference)
//
#include <hip/hip_runtime.h>
#include <hip/hip_bf16.h>
#include <cstdint>
#include <cstddef>

// ---- problem constants ----
#define BATCH 2
#define SEQ   2048
#define DM    1024
#define NH    16
#define DK    64
#define MROWS (BATCH*SEQ)   // 4096

typedef __bf16 bf16;
typedef float  f32x4  __attribute__((ext_vector_type(4)));
typedef bf16   bf16x8 __attribute__((ext_vector_type(8)));
typedef bf16   bf16x4 __attribute__((ext_vector_type(4)));

// verified (m89/m120): A[m=lane&15][k=(lane>>4)*8+j], B[n=lane&15][k=(lane>>4)*8+j],
// C/D: col(n)=lane&15, row(m)=(lane>>4)*4+reg
#define MFMA32(a, b, c) __builtin_amdgcn_mfma_f32_16x16x32_bf16(a, b, c, 0, 0, 0)

// async global->LDS, 16B per lane; LDS dest is wave-uniform base + lane*16
__device__ __forceinline__ void llds16(const void* gc, void* l) {
    void* g = (void*)gc;
    __builtin_amdgcn_global_load_lds(
        (__attribute__((address_space(1))) uint32_t*)g,
        (__attribute__((address_space(3))) uint32_t*)l,
        16, 0, 0);
}

// convert 8 fp32 (two float4) -> bf16x8 and store 16B to LDS
__device__ __forceinline__ void cvt_store(bf16* dst, f32x4 x, f32x4 y) {
    bf16x8 p;
    p[0] = (bf16)x[0]; p[1] = (bf16)x[1]; p[2] = (bf16)x[2]; p[3] = (bf16)x[3];
    p[4] = (bf16)y[0]; p[5] = (bf16)y[1]; p[6] = (bf16)y[2]; p[7] = (bf16)y[3];
    *(bf16x8*)dst = p;
}

// ---------------- GEMM mainloop on fp32 inputs: BK=32, dbuf, 1 barrier/k-step ----------------
// acc = A[M,K] * B[N,K]^T on a 128x128 tile; A,B are fp32 in HBM, converted to bf16
// during staging (kills the separate convert kernel). Pipeline per step s:
//   barrier -> issue fp32 loads(s+1) -> MFMA on LDS[s&1] -> (vmcnt wait) cvt+ds_write
//   into LDS[(s+1)&1] -> next barrier.
// The vmcnt wait sits after a full MFMA phase, so the barrier drain is ~free.
__device__ __forceinline__ void gemm_main_f32(const float* __restrict__ A, const float* __restrict__ B,
                                              int m0, int n0, f32x4 acc[4][4]) {
    constexpr int K = DM, BK = 32, NS = K / BK;
    __shared__ bf16 sA[2][128 * BK];
    __shared__ bf16 sB[2][128 * BK];
    const int tid = threadIdx.x;
    const int l = tid & 63, w = tid >> 6;
    const int quad = l >> 4, l15 = l & 15;
    const int wm = w & 1, wn = w >> 1;
    // staging: thread t covers rows {t>>2, t>>2+64}, cols (t&3)*8 .. +7 (quad = 128B contig)
    const int r0 = tid >> 2, c0 = (tid & 3) * 8;

    const float* pa0 = A + (size_t)(m0 + r0) * K + c0;
    const float* pa1 = A + (size_t)(m0 + r0 + 64) * K + c0;
    const float* pb0 = B + (size_t)(n0 + r0) * K + c0;
    const float* pb1 = B + (size_t)(n0 + r0 + 64) * K + c0;

    f32x4 La[4], Lb[4];
    // prologue: stage step 0
    La[0] = *(const f32x4*)(pa0);     La[1] = *(const f32x4*)(pa0 + 4);
    La[2] = *(const f32x4*)(pa1);     La[3] = *(const f32x4*)(pa1 + 4);
    Lb[0] = *(const f32x4*)(pb0);     Lb[1] = *(const f32x4*)(pb0 + 4);
    Lb[2] = *(const f32x4*)(pb1);     Lb[3] = *(const f32x4*)(pb1 + 4);
    cvt_store(&sA[0][r0 * BK + c0], La[0], La[1]);
    cvt_store(&sA[0][(r0 + 64) * BK + c0], La[2], La[3]);
    cvt_store(&sB[0][r0 * BK + c0], Lb[0], Lb[1]);
    cvt_store(&sB[0][(r0 + 64) * BK + c0], Lb[2], Lb[3]);

    for (int s = 0; s < NS; ++s) {
        __syncthreads();                 // writes of step s (done last iter) visible
        const int cur = s & 1;
        const int k1 = (s + 1) * BK;
        if (s + 1 < NS) {
            La[0] = *(const f32x4*)(pa0 + k1);  La[1] = *(const f32x4*)(pa0 + k1 + 4);
            La[2] = *(const f32x4*)(pa1 + k1);  La[3] = *(const f32x4*)(pa1 + k1 + 4);
            Lb[0] = *(const f32x4*)(pb0 + k1);  Lb[1] = *(const f32x4*)(pb0 + k1 + 4);
            Lb[2] = *(const f32x4*)(pb1 + k1);  Lb[3] = *(const f32x4*)(pb1 + k1 + 4);
        }

        bf16x8 af[4], bfr[4];
#pragma unroll
        for (int mi = 0; mi < 4; ++mi)
            af[mi] = *(const bf16x8*)&sA[cur][(wm * 64 + mi * 16 + l15) * BK + quad * 8];
#pragma unroll
        for (int ni = 0; ni < 4; ++ni)
            bfr[ni] = *(const bf16x8*)&sB[cur][(wn * 64 + ni * 16 + l15) * BK + quad * 8];
#pragma unroll
        for (int mi = 0; mi < 4; ++mi)
#pragma unroll
            for (int ni = 0; ni < 4; ++ni)
                acc[mi][ni] = MFMA32(af[mi], bfr[ni], acc[mi][ni]);

        if (s + 1 < NS) {
            bf16* dA = (bf16*)&sA[cur ^ 1][0];
            bf16* dB = (bf16*)&sB[cur ^ 1][0];
            cvt_store(&dA[r0 * BK + c0], La[0], La[1]);
            cvt_store(&dA[(r0 + 64) * BK + c0], La[2], La[3]);
            cvt_store(&dB[r0 * BK + c0], Lb[0], Lb[1]);
            cvt_store(&dB[(r0 + 64) * BK + c0], Lb[2], Lb[3]);
        }
    }
}

// ---- merged Q/K/V projections from fp32 inputs, frag-major epilogues ----
// Qf/Kf entry (bh, s16 = s>>4, chunk = d>>5): lane l, elem e holds
//   [s-in-16 = l&15][d-in-32 = (l>>4)*8 + e]   (= MFMA A/B-operand order)
// Vf entry (bh, kc = s>>5, dtile = d>>4): lane l, elem e holds
//   [d-in-16 = l&15][key-in-32 = (l>>4)*8 + e]
__global__ __launch_bounds__(256) void k_gemm_qkv(
    const float* __restrict__ q, const float* __restrict__ k, const float* __restrict__ v,
    const float* __restrict__ wq, const float* __restrict__ wk, const float* __restrict__ wv,
    const float* __restrict__ bq, const float* __restrict__ bk, const float* __restrict__ bv,
    bf16* __restrict__ Qf, bf16* __restrict__ Kf, bf16* __restrict__ Vf) {
    const int z = blockIdx.z;
    const float* A; const float* B; const float* bias;
    int m0, n0;
    if (z == 2) {
        A = v; B = wv; bias = bv;
        m0 = blockIdx.x * 128;    // s block (M = 4096)
        n0 = blockIdx.y * 128;    // feature block (N = 1024)
    } else {
        A = z ? wk : wq; B = z ? k : q; bias = z ? bk : bq;
        m0 = blockIdx.y * 128;    // feature block (M = 1024)
        n0 = blockIdx.x * 128;    // s block (N = 4096)
    }
    f32x4 acc[4][4] = {};
    gemm_main_f32(A, B, m0, n0, acc);

    const int tid = threadIdx.x, l = tid & 63, w = tid >> 6;
    const int quad = l >> 4, l15 = l & 15;
    const int wm = w & 1, wn = w >> 1;

    if (z == 2) {
        // V epilogue: acc element = V[s = m0+wm*64+mi*16+quad*4+r][d = n0+wn*64+ni*16+l15]
#pragma unroll
        for (int ni = 0; ni < 4; ++ni) {
            int dcol = n0 + wn * 64 + ni * 16 + l15;
            int hh2 = dcol >> 6;                 // head
            int dtile = (dcol >> 4) & 3;         // (d&63)>>4
            float bias_v = bias[dcol];
#pragma unroll
            for (int mi = 0; mi < 4; ++mi) {
                int srow = m0 + wm * 64 + mi * 16;
                int bb = srow >> 11, sl = srow & 2047;
                int kc = sl >> 5;
                int qp = 2 * (mi & 1) + (quad >> 1);   // (key32)>>3
                bf16x4 pack;
#pragma unroll
                for (int r = 0; r < 4; ++r)
                    pack[r] = (bf16)(acc[mi][ni][r] + bias_v);
                size_t entry = ((size_t)(bb * NH + hh2) * 64 + kc) * 4 + dtile;
                *(bf16x4*)(Vf + entry * 512 + (size_t)(qp * 16 + l15) * 8 + (quad & 1) * 4) = pack;
            }
        }
    } else {
        // Q/K epilogue: acc element = D[feature = m0+wm*64+mi*16+quad*4+r][s = n0+wn*64+ni*16+l15]
        bf16* out = z ? Kf : Qf;
        const float scale = z ? 1.0f : 0.18033688f;   // Q carries 0.125 * log2(e)
        float bias_rv[4][4];
#pragma unroll
        for (int mi = 0; mi < 4; ++mi)
#pragma unroll
            for (int r = 0; r < 4; ++r)
                bias_rv[mi][r] = bias[m0 + wm * 64 + mi * 16 + quad * 4 + r];
#pragma unroll
        for (int ni = 0; ni < 4; ++ni) {
            int scol = n0 + wn * 64 + ni * 16 + l15;
            int bb = scol >> 11, s = scol & 2047;
            int s16 = s >> 4;
#pragma unroll
            for (int mi = 0; mi < 4; ++mi) {
                int drow = m0 + wm * 64 + mi * 16;
                int hh2 = (drow >> 6) & 15;
                int chunk = (drow & 63) >> 5;
                int qp = 2 * (mi & 1) + (quad >> 1);   // (d32)>>3
                bf16x4 pack;
#pragma unroll
                for (int r = 0; r < 4; ++r)
                    pack[r] = (bf16)((acc[mi][ni][r] + bias_rv[mi][r]) * scale);
                size_t entry = ((size_t)(bb * NH + hh2) * 128 + s16) * 2 + chunk;
                *(bf16x4*)(out + entry * 512 + (size_t)(qp * 16 + l15) * 8 + (quad & 1) * 4) = pack;
            }
        }
    }
}

// ---- output projection: X (bf16) via llds16-dbuf, wo (fp32) via reg-pipeline ----
__global__ __launch_bounds__(256) void k_gemm_out(
    const bf16* __restrict__ X, const float* __restrict__ wo,
    const float* __restrict__ bo, float* __restrict__ out) {
    constexpr int K = DM, BK = 32, NS = K / BK;
    const int m0 = blockIdx.y * 128, n0 = blockIdx.x * 64;
    __shared__ bf16 sA[2][128 * BK];
    __shared__ bf16 sB[2][64 * BK];
    const int tid = threadIdx.x;
    const int l = tid & 63, w = tid >> 6;
    const int quad = l >> 4, l15 = l & 15;
    const int wm = w & 1, wn = w >> 1;
    const int srow = l >> 2, scol = (l & 3) * 8;      // llds16 staging (bf16)
    const int rB = tid >> 2, cB = (tid & 3) * 8;      // wo staging (fp32), rows 0..63

    const float* pb = wo + (size_t)(n0 + rB) * K + cB;

    // prologue: stage step 0
#pragma unroll
    for (int i = 0; i < 2; ++i) {
        int r16 = w * 32 + i * 16;
        llds16(X + (size_t)(m0 + r16 + srow) * K + scol, &sA[0][r16 * BK]);
    }
    {
        f32x4 b0 = *(const f32x4*)(pb), b1 = *(const f32x4*)(pb + 4);
        cvt_store(&sB[0][rB * BK + cB], b0, b1);
    }

    f32x4 acc[4][2] = {};
    f32x4 Lb0, Lb1;
    for (int s = 0; s < NS; ++s) {
        __syncthreads();
        const int cur = s & 1;
        const int k1 = (s + 1) * BK;
        if (s + 1 < NS) {
#pragma unroll
            for (int i = 0; i < 2; ++i) {
                int r16 = w * 32 + i * 16;
                llds16(X + (size_t)(m0 + r16 + srow) * K + k1 + scol, &sA[cur ^ 1][r16 * BK]);
            }
            Lb0 = *(const f32x4*)(pb + k1);
            Lb1 = *(const f32x4*)(pb + k1 + 4);
        }

        bf16x8 af[4], bfr[2];
#pragma unroll
        for (int mi = 0; mi < 4; ++mi)
            af[mi] = *(const bf16x8*)&sA[cur][(wm * 64 + mi * 16 + l15) * BK + quad * 8];
#pragma unroll
        for (int ni = 0; ni < 2; ++ni)
            bfr[ni] = *(const bf16x8*)&sB[cur][(wn * 32 + ni * 16 + l15) * BK + quad * 8];
#pragma unroll
        for (int mi = 0; mi < 4; ++mi)
#pragma unroll
            for (int ni = 0; ni < 2; ++ni)
                acc[mi][ni] = MFMA32(af[mi], bfr[ni], acc[mi][ni]);

        if (s + 1 < NS)
            cvt_store(&sB[cur ^ 1][rB * BK + cB], Lb0, Lb1);
    }
#pragma unroll
    for (int mi = 0; mi < 4; ++mi)
#pragma unroll
        for (int ni = 0; ni < 2; ++ni) {
            int col = n0 + wn * 32 + ni * 16 + l15;
            float bias_v = bo[col];
            int rbase = m0 + wm * 64 + mi * 16 + quad * 4;
#pragma unroll
            for (int r = 0; r < 4; ++r)
                out[(size_t)(rbase + r) * DM + col] = acc[mi][ni][r] + bias_v;
        }
}

// ---------------- causal flash attention, double-buffered block-shared K/V ----------------
// grid (bh=32, 32): qt = 31 - y (LPT); XCD = linear_id&7 = bh&7 pins each bh's K/V.
// Block = 256 thr = 4 waves on one 64-query tile. K/V j-tile (16 entries, 16KB)
// double-buffered: ONE barrier per iter, drain waits on loads issued a full iter ago.
// S^T = K·Q^T keeps query = l15 in-lane (fixed-m exp2 softmax, per-lane partials).
__global__ __launch_bounds__(256, 3) void k_flash(const bf16* __restrict__ Qf,
                                                  const bf16* __restrict__ Kf,
                                                  const bf16* __restrict__ Vf,
                                                  bf16* __restrict__ X) {
    const int bh = blockIdx.x;
    const int qt = 31 - (int)blockIdx.y;      // LPT order
    const int b = bh >> 4, h = bh & 15;
    const int tid = threadIdx.x, w = tid >> 6, l = tid & 63;
    const int quad = l >> 4, l15 = l & 15;
    __shared__ bf16 sKV[2][16 * 512];         // [buf][e]: e 0..7 = K (ni*2+c), 8..15 = V (8+c*4+dt)
    __shared__ bf16 P[4][16 * 72];            // per-wave P^T scratch
    bf16* Pw = P[w];

    const bf16* qfp = Qf + (size_t)bh * 128 * 1024;
    const bf16* kfp = Kf + (size_t)bh * 128 * 1024;
    const bf16* vfp = Vf + (size_t)bh * 64 * 4 * 512;

    const int qt16 = qt * 4 + w;              // wave's 16-query tile (s16 index)
    const int qglob = qt16 * 16 + l15;

    // persistent Q B-frags (d 0..31, 32..63)
    bf16x8 qf[2];
#pragma unroll
    for (int c = 0; c < 2; ++c)
        qf[c] = *(const bf16x8*)(qfp + ((size_t)qt16 * 2 + c) * 512 + (size_t)l * 8);

    f32x4 o[4] = {};            // O^T: row = d-in-16 (per dtile), col = query = l15
    float lp = 0.f;             // per-lane partial softmax denom

    // preload tile 0: wave w stages entries w*4..w*4+3
#pragma unroll
    for (int i = 0; i < 4; ++i) {
        int e = w * 4 + i;
        const bf16* src = (e < 8) ? kfp + ((size_t)e) * 512
                                  : vfp + ((size_t)(e - 8)) * 512;
        llds16(src + (size_t)l * 8, &sKV[0][e * 512]);
    }

    for (int j = 0; j <= qt; ++j) {
        __syncthreads();        // staging of tile j (issued last iter) now visible
        const bf16* cur = sKV[j & 1];
        if (j < qt) {
            int j1 = j + 1;
#pragma unroll
            for (int i = 0; i < 4; ++i) {
                int e = w * 4 + i;
                const bf16* src = (e < 8) ? kfp + ((size_t)(j1 * 8 + e)) * 512
                                          : vfp + ((size_t)(j1 * 8 + (e - 8))) * 512;
                llds16(src + (size_t)l * 8, (void*)&sKV[j1 & 1][e * 512]);
            }
        }

        // ---- S^T = K·Q^T per 16-key subtile (frags from LDS, stride-1) ----
        f32x4 st[4];
#pragma unroll
        for (int ni = 0; ni < 4; ++ni) {
            bf16x8 k0 = *(const bf16x8*)&cur[(size_t)(ni * 2 + 0) * 512 + l * 8];
            bf16x8 k1 = *(const bf16x8*)&cur[(size_t)(ni * 2 + 1) * 512 + l * 8];
            f32x4 zz = {};
            zz = MFMA32(k0, qf[0], zz);
            st[ni] = MFMA32(k1, qf[1], zz);
        }

        // ---- fixed-m softmax (log2 domain) + P^T -> wave-private LDS ----
        const bool diag = (j == qt);
#pragma unroll
        for (int ni = 0; ni < 4; ++ni) {
            bf16x4 ev;
#pragma unroll
            for (int r = 0; r < 4; ++r) {
                float s = st[ni][r];
                if (diag) {
                    int key = j * 64 + ni * 16 + quad * 4 + r;
                    if (key > qglob) s = -1e30f;
                }
                float e = __builtin_amdgcn_exp2f(s);
                lp += e;
                ev[r] = (bf16)e;
            }
            *(bf16x4*)&Pw[l15 * 72 + ni * 16 + quad * 4] = ev;
        }

        // ---- O^T += V^T·P^T per 32-key chunk ----
#pragma unroll
        for (int c = 0; c < 2; ++c) {
            bf16x8 pb = *(const bf16x8*)&Pw[l15 * 72 + c * 32 + quad * 8];
#pragma unroll
            for (int dt = 0; dt < 4; ++dt) {
                bf16x8 vv = *(const bf16x8*)&cur[(size_t)(8 + c * 4 + dt) * 512 + l * 8];
                o[dt] = MFMA32(vv, pb, o[dt]);
            }
        }
    }

    // ---- reduce denom across quads (queries are per-lane) ----
    lp += __shfl_xor(lp, 16, 64);
    lp += __shfl_xor(lp, 32, 64);
    float rv = 1.f / lp;

    // ---- normalize, repack via wave-private LDS, coalesced store ----
#pragma unroll
    for (int dt = 0; dt < 4; ++dt) {
        bf16x4 pk;
#pragma unroll
        for (int r = 0; r < 4; ++r)
            pk[r] = (bf16)(o[dt][r] * rv);
        *(bf16x4*)&Pw[l15 * 72 + dt * 16 + quad * 4] = pk;
    }
#pragma unroll
    for (int i = 0; i < 2; ++i) {
        int row = i * 8 + (l >> 3);
        bf16x8 vv = *(const bf16x8*)&Pw[row * 72 + (l & 7) * 8];
        *(bf16x8*)(X + (size_t)(b * SEQ + qt16 * 16 + row) * DM + h * 64 + (l & 7) * 8) = vv;
    }
}

// ---------------- launcher ----------------
extern "C" void kernel_launch(void* const* d_in, const int* in_sizes, int n_in,
                              void* d_out, int out_size, void* d_ws, size_t ws_size,
                              hipStream_t stream) {
    const float* q  = (const float*)d_in[0];
    const float* k  = (const float*)d_in[1];
    const float* v  = (const float*)d_in[2];
    // d_in[3] = mask: causal tril, handled analytically
    const float* wq = (const float*)d_in[4];
    const float* bq = (const float*)d_in[5];
    const float* wk = (const float*)d_in[6];
    const float* bk = (const float*)d_in[7];
    const float* wv = (const float*)d_in[8];
    const float* bv = (const float*)d_in[9];
    const float* wo = (const float*)d_in[10];
    const float* bo = (const float*)d_in[11];
    float* out = (float*)d_out;

    uint8_t* ws = (uint8_t*)d_ws;
    const size_t SZ_ACT = (size_t)MROWS * DM * sizeof(bf16);  // 8 MB
    bf16* Qf = (bf16*)(ws);
    bf16* Kf = (bf16*)(ws + SZ_ACT);
    bf16* Vf = (bf16*)(ws + 2 * SZ_ACT);
    bf16* X  = (bf16*)(ws + 3 * SZ_ACT);
    // total: 32 MB

    // 1) merged Q/K/V projections straight from fp32 (convert fused into staging)
    k_gemm_qkv<<<dim3(32, 8, 3), 256, 0, stream>>>(
        q, k, v, wq, wk, wv, bq, bk, bv, Qf, Kf, Vf);
    // 2) causal flash attention (64-query blocks, dbuf K/V, 1 barrier/iter)
    k_flash<<<dim3(BATCH * NH, SEQ / 64), 256, 0, stream>>>(Qf, Kf, Vf, X);
    // 3) output projection -> fp32 (128x64 tiles, dbuf, wo staged from fp32)
    k_gemm_out<<<dim3(DM / 64, MROWS / 128), 256, 0, stream>>>(X, wo, bo, out);
}

// Round 11
// 229.742 us; speedup vs baseline: 1.0669x; 1.0669x over previous
//
#include <hip/hip_runtime.h>
#include <hip/hip_bf16.h>
#include <cstdint>
#include <cstddef>

// ---- problem constants ----
#define BATCH 2
#define SEQ   2048
#define DM    1024
#define NH    16
#define DK    64
#define MROWS (BATCH*SEQ)   // 4096

typedef __bf16 bf16;
typedef float  f32x4  __attribute__((ext_vector_type(4)));
typedef bf16   bf16x8 __attribute__((ext_vector_type(8)));
typedef bf16   bf16x4 __attribute__((ext_vector_type(4)));

// verified (m89/m120): A[m=lane&15][k=(lane>>4)*8+j], B[n=lane&15][k=(lane>>4)*8+j],
// C/D: col(n)=lane&15, row(m)=(lane>>4)*4+reg
#define MFMA32(a, b, c) __builtin_amdgcn_mfma_f32_16x16x32_bf16(a, b, c, 0, 0, 0)

// async global->LDS, 16B per lane; LDS dest is wave-uniform base + lane*16
__device__ __forceinline__ void llds16(const void* gc, void* l) {
    void* g = (void*)gc;
    __builtin_amdgcn_global_load_lds(
        (__attribute__((address_space(1))) uint32_t*)g,
        (__attribute__((address_space(3))) uint32_t*)l,
        16, 0, 0);
}

// ---------------- fused fp32 -> bf16 convert (q,k,v + 4 weights) ----------------
__global__ __launch_bounds__(256) void k_convert(
    const float* __restrict__ q, const float* __restrict__ k, const float* __restrict__ v,
    const float* __restrict__ wq, const float* __restrict__ wk, const float* __restrict__ wv,
    const float* __restrict__ wo,
    bf16* __restrict__ qb, bf16* __restrict__ kb, bf16* __restrict__ vb,
    bf16* __restrict__ wqb, bf16* __restrict__ wkb, bf16* __restrict__ wvb,
    bf16* __restrict__ wob) {
    long t = (long)blockIdx.x * blockDim.x + threadIdx.x;   // one float4 per thread
    const long NQ = (long)MROWS * DM / 4;
    const long NW = (long)DM * DM / 4;
    const float* src; bf16* dst; long off;
    if (t < NQ)            { src = q;  dst = qb;  off = t; }
    else if (t < 2*NQ)     { src = k;  dst = kb;  off = t - NQ; }
    else if (t < 3*NQ)     { src = v;  dst = vb;  off = t - 2*NQ; }
    else {
        long u = t - 3*NQ;
        if (u < NW)        { src = wq; dst = wqb; off = u; }
        else if (u < 2*NW) { src = wk; dst = wkb; off = u - NW; }
        else if (u < 3*NW) { src = wv; dst = wvb; off = u - 2*NW; }
        else               { src = wo; dst = wob; off = u - 3*NW; }
    }
    f32x4 x = *(const f32x4*)(src + off * 4);
    bf16x4 y;
    y[0] = (bf16)x[0]; y[1] = (bf16)x[1]; y[2] = (bf16)x[2]; y[3] = (bf16)x[3];
    *(bf16x4*)(dst + off * 4) = y;
}

// ---- merged Q/K/V projections: 128(M)x64(N) tiles, 1536 blocks = 6/CU ----
// Static 2-barrier m97 staging (R6-proven low-VALU), BK=32. Higher co-residency
// hides the barrier drains (the untried lever: all 3-block/CU variants = 51-80us).
// Qf/Kf entry (bh, s16 = s>>4, chunk = d>>5): lane l, elem e holds
//   [s-in-16 = l&15][d-in-32 = (l>>4)*8 + e]   (= MFMA A/B-operand order)
// Vf entry (bh, kc = s>>5, dtile = d>>4): lane l, elem e holds
//   [d-in-16 = l&15][key-in-32 = (l>>4)*8 + e]
__global__ __launch_bounds__(256) void k_gemm_qkv(
    const bf16* __restrict__ qb, const bf16* __restrict__ kb, const bf16* __restrict__ vb,
    const bf16* __restrict__ wqb, const bf16* __restrict__ wkb, const bf16* __restrict__ wvb,
    const float* __restrict__ bq, const float* __restrict__ bk, const float* __restrict__ bv,
    bf16* __restrict__ Qf, bf16* __restrict__ Kf, bf16* __restrict__ Vf) {
    const int z = blockIdx.z;
    const int bid = blockIdx.x;
    const bf16* A; const bf16* B; const float* bias;
    int m0, n0;
    if (z == 2) {
        A = vb; B = wvb; bias = bv;
        m0 = (bid >> 4) * 128;        // s block (32 of them)
        n0 = (bid & 15) * 64;         // feature block (16)
    } else {
        A = z ? wkb : wqb; B = z ? kb : qb; bias = z ? bk : bq;
        m0 = (bid >> 6) * 128;        // feature block (8)
        n0 = (bid & 63) * 64;         // s block (64)
    }

    constexpr int K = DM, BK = 32;
    __shared__ bf16 sA[128 * BK];
    __shared__ bf16 sB[64 * BK];
    const int tid = threadIdx.x;
    const int l = tid & 63, w = tid >> 6;
    const int quad = l >> 4, l15 = l & 15;
    const int wm = w & 1, wn = w >> 1;
    const int srow = l >> 2, scol = (l & 3) * 8;

    f32x4 acc[4][2] = {};
    for (int k0 = 0; k0 < K; k0 += BK) {
#pragma unroll
        for (int i = 0; i < 2; ++i) {
            int r16 = w * 32 + i * 16;
            llds16(A + (size_t)(m0 + r16 + srow) * K + k0 + scol, &sA[r16 * BK]);
        }
        llds16(B + (size_t)(n0 + w * 16 + srow) * K + k0 + scol, &sB[w * 16 * BK]);
        __syncthreads();

        bf16x8 af[4], bfr[2];
#pragma unroll
        for (int mi = 0; mi < 4; ++mi)
            af[mi] = *(const bf16x8*)&sA[(wm * 64 + mi * 16 + l15) * BK + quad * 8];
#pragma unroll
        for (int ni = 0; ni < 2; ++ni)
            bfr[ni] = *(const bf16x8*)&sB[(wn * 32 + ni * 16 + l15) * BK + quad * 8];
#pragma unroll
        for (int mi = 0; mi < 4; ++mi)
#pragma unroll
            for (int ni = 0; ni < 2; ++ni)
                acc[mi][ni] = MFMA32(af[mi], bfr[ni], acc[mi][ni]);
        __syncthreads();
    }

    if (z == 2) {
        // V epilogue: acc element = V[s = m0+wm*64+mi*16+quad*4+r][d = n0+wn*32+ni*16+l15]
#pragma unroll
        for (int ni = 0; ni < 2; ++ni) {
            int dcol = n0 + wn * 32 + ni * 16 + l15;
            int hh2 = dcol >> 6;                 // head
            int dtile = (dcol >> 4) & 3;         // (d&63)>>4
            float bias_v = bias[dcol];
#pragma unroll
            for (int mi = 0; mi < 4; ++mi) {
                int srw = m0 + wm * 64 + mi * 16;
                int bb = srw >> 11, sl = srw & 2047;
                int kc = sl >> 5;
                int qp = 2 * (mi & 1) + (quad >> 1);   // (key32)>>3
                bf16x4 pack;
#pragma unroll
                for (int r = 0; r < 4; ++r)
                    pack[r] = (bf16)(acc[mi][ni][r] + bias_v);
                size_t entry = ((size_t)(bb * NH + hh2) * 64 + kc) * 4 + dtile;
                *(bf16x4*)(Vf + entry * 512 + (size_t)(qp * 16 + l15) * 8 + (quad & 1) * 4) = pack;
            }
        }
    } else {
        // Q/K epilogue: acc element = D[feature = m0+wm*64+mi*16+quad*4+r][s = n0+wn*32+ni*16+l15]
        bf16* out = z ? Kf : Qf;
        const float scale = z ? 1.0f : 0.18033688f;   // Q carries 0.125 * log2(e)
        float bias_rv[4][4];
#pragma unroll
        for (int mi = 0; mi < 4; ++mi)
#pragma unroll
            for (int r = 0; r < 4; ++r)
                bias_rv[mi][r] = bias[m0 + wm * 64 + mi * 16 + quad * 4 + r];
#pragma unroll
        for (int ni = 0; ni < 2; ++ni) {
            int scolg = n0 + wn * 32 + ni * 16 + l15;
            int bb = scolg >> 11, s = scolg & 2047;
            int s16 = s >> 4;
#pragma unroll
            for (int mi = 0; mi < 4; ++mi) {
                int drow = m0 + wm * 64 + mi * 16;
                int hh2 = (drow >> 6) & 15;
                int chunk = (drow & 63) >> 5;
                int qp = 2 * (mi & 1) + (quad >> 1);   // (d32)>>3
                bf16x4 pack;
#pragma unroll
                for (int r = 0; r < 4; ++r)
                    pack[r] = (bf16)((acc[mi][ni][r] + bias_rv[mi][r]) * scale);
                size_t entry = ((size_t)(bb * NH + hh2) * 128 + s16) * 2 + chunk;
                *(bf16x4*)(out + entry * 512 + (size_t)(qp * 16 + l15) * 8 + (quad & 1) * 4) = pack;
            }
        }
    }
}

// ---- output projection: 128(M)x64(N) tiles, m97 staging, dbuf, 1 barrier/k-step ----
__global__ __launch_bounds__(256) void k_gemm_out(
    const bf16* __restrict__ X, const bf16* __restrict__ wob,
    const float* __restrict__ bo, float* __restrict__ out) {
    constexpr int K = DM, BK = 32, NS = K / BK;
    const int m0 = blockIdx.y * 128, n0 = blockIdx.x * 64;
    __shared__ bf16 sA[2][128 * BK];
    __shared__ bf16 sB[2][64 * BK];
    const int tid = threadIdx.x;
    const int l = tid & 63, w = tid >> 6;
    const int quad = l >> 4, l15 = l & 15;
    const int wm = w & 1, wn = w >> 1;
    const int srow = l >> 2, scol = (l & 3) * 8;

#pragma unroll
    for (int i = 0; i < 2; ++i) {
        int r16 = w * 32 + i * 16;
        llds16(X + (size_t)(m0 + r16 + srow) * K + scol, &sA[0][r16 * BK]);
    }
    llds16(wob + (size_t)(n0 + w * 16 + srow) * K + scol, &sB[0][w * 16 * BK]);

    f32x4 acc[4][2] = {};
    for (int s = 0; s < NS; ++s) {
        __syncthreads();
        const int cur = s & 1;
        if (s + 1 < NS) {
            const int k0 = (s + 1) * BK;
#pragma unroll
            for (int i = 0; i < 2; ++i) {
                int r16 = w * 32 + i * 16;
                llds16(X + (size_t)(m0 + r16 + srow) * K + k0 + scol, &sA[cur ^ 1][r16 * BK]);
            }
            llds16(wob + (size_t)(n0 + w * 16 + srow) * K + k0 + scol, &sB[cur ^ 1][w * 16 * BK]);
        }

        bf16x8 af[4], bfr[2];
#pragma unroll
        for (int mi = 0; mi < 4; ++mi)
            af[mi] = *(const bf16x8*)&sA[cur][(wm * 64 + mi * 16 + l15) * BK + quad * 8];
#pragma unroll
        for (int ni = 0; ni < 2; ++ni)
            bfr[ni] = *(const bf16x8*)&sB[cur][(wn * 32 + ni * 16 + l15) * BK + quad * 8];
#pragma unroll
        for (int mi = 0; mi < 4; ++mi)
#pragma unroll
            for (int ni = 0; ni < 2; ++ni)
                acc[mi][ni] = MFMA32(af[mi], bfr[ni], acc[mi][ni]);
    }
#pragma unroll
    for (int mi = 0; mi < 4; ++mi)
#pragma unroll
        for (int ni = 0; ni < 2; ++ni) {
            int col = n0 + wn * 32 + ni * 16 + l15;
            float bias_v = bo[col];
            int rbase = m0 + wm * 64 + mi * 16 + quad * 4;
#pragma unroll
            for (int r = 0; r < 4; ++r)
                out[(size_t)(rbase + r) * DM + col] = acc[mi][ni][r] + bias_v;
        }
}

// ---------------- causal flash attention, double-buffered block-shared K/V ----------------
// grid (bh=32, 32): qt = 31 - y (LPT); XCD = linear_id&7 = bh&7 pins each bh's K/V.
// Block = 256 thr = 4 waves on one 64-query tile. K/V j-tile (16 entries, 16KB)
// double-buffered: ONE barrier per iter, drain waits on loads issued a full iter ago.
// S^T = K·Q^T keeps query = l15 in-lane (fixed-m exp2 softmax, per-lane partials).
__global__ __launch_bounds__(256, 3) void k_flash(const bf16* __restrict__ Qf,
                                                  const bf16* __restrict__ Kf,
                                                  const bf16* __restrict__ Vf,
                                                  bf16* __restrict__ X) {
    const int bh = blockIdx.x;
    const int qt = 31 - (int)blockIdx.y;      // LPT order
    const int b = bh >> 4, h = bh & 15;
    const int tid = threadIdx.x, w = tid >> 6, l = tid & 63;
    const int quad = l >> 4, l15 = l & 15;
    __shared__ bf16 sKV[2][16 * 512];         // [buf][e]: e 0..7 = K (ni*2+c), 8..15 = V (8+c*4+dt)
    __shared__ bf16 P[4][16 * 72];            // per-wave P^T scratch
    bf16* Pw = P[w];

    const bf16* qfp = Qf + (size_t)bh * 128 * 1024;
    const bf16* kfp = Kf + (size_t)bh * 128 * 1024;
    const bf16* vfp = Vf + (size_t)bh * 64 * 4 * 512;

    const int qt16 = qt * 4 + w;              // wave's 16-query tile (s16 index)
    const int qglob = qt16 * 16 + l15;

    // persistent Q B-frags (d 0..31, 32..63)
    bf16x8 qf[2];
#pragma unroll
    for (int c = 0; c < 2; ++c)
        qf[c] = *(const bf16x8*)(qfp + ((size_t)qt16 * 2 + c) * 512 + (size_t)l * 8);

    f32x4 o[4] = {};            // O^T: row = d-in-16 (per dtile), col = query = l15
    float lp = 0.f;             // per-lane partial softmax denom

    // preload tile 0: wave w stages entries w*4..w*4+3
#pragma unroll
    for (int i = 0; i < 4; ++i) {
        int e = w * 4 + i;
        const bf16* src = (e < 8) ? kfp + ((size_t)e) * 512
                                  : vfp + ((size_t)(e - 8)) * 512;
        llds16(src + (size_t)l * 8, &sKV[0][e * 512]);
    }

    for (int j = 0; j <= qt; ++j) {
        __syncthreads();        // staging of tile j (issued last iter) now visible
        const bf16* cur = sKV[j & 1];
        if (j < qt) {
            int j1 = j + 1;
#pragma unroll
            for (int i = 0; i < 4; ++i) {
                int e = w * 4 + i;
                const bf16* src = (e < 8) ? kfp + ((size_t)(j1 * 8 + e)) * 512
                                          : vfp + ((size_t)(j1 * 8 + (e - 8))) * 512;
                llds16(src + (size_t)l * 8, (void*)&sKV[j1 & 1][e * 512]);
            }
        }

        // ---- S^T = K·Q^T per 16-key subtile (frags from LDS, stride-1) ----
        f32x4 st[4];
#pragma unroll
        for (int ni = 0; ni < 4; ++ni) {
            bf16x8 k0 = *(const bf16x8*)&cur[(size_t)(ni * 2 + 0) * 512 + l * 8];
            bf16x8 k1 = *(const bf16x8*)&cur[(size_t)(ni * 2 + 1) * 512 + l * 8];
            f32x4 zz = {};
            zz = MFMA32(k0, qf[0], zz);
            st[ni] = MFMA32(k1, qf[1], zz);
        }

        // ---- fixed-m softmax (log2 domain) + P^T -> wave-private LDS ----
        const bool diag = (j == qt);
#pragma unroll
        for (int ni = 0; ni < 4; ++ni) {
            bf16x4 ev;
#pragma unroll
            for (int r = 0; r < 4; ++r) {
                float s = st[ni][r];
                if (diag) {
                    int key = j * 64 + ni * 16 + quad * 4 + r;
                    if (key > qglob) s = -1e30f;
                }
                float e = __builtin_amdgcn_exp2f(s);
                lp += e;
                ev[r] = (bf16)e;
            }
            *(bf16x4*)&Pw[l15 * 72 + ni * 16 + quad * 4] = ev;
        }

        // ---- O^T += V^T·P^T per 32-key chunk ----
#pragma unroll
        for (int c = 0; c < 2; ++c) {
            bf16x8 pb = *(const bf16x8*)&Pw[l15 * 72 + c * 32 + quad * 8];
#pragma unroll
            for (int dt = 0; dt < 4; ++dt) {
                bf16x8 vv = *(const bf16x8*)&cur[(size_t)(8 + c * 4 + dt) * 512 + l * 8];
                o[dt] = MFMA32(vv, pb, o[dt]);
            }
        }
    }

    // ---- reduce denom across quads (queries are per-lane) ----
    lp += __shfl_xor(lp, 16, 64);
    lp += __shfl_xor(lp, 32, 64);
    float rv = 1.f / lp;

    // ---- normalize, repack via wave-private LDS, coalesced store ----
#pragma unroll
    for (int dt = 0; dt < 4; ++dt) {
        bf16x4 pk;
#pragma unroll
        for (int r = 0; r < 4; ++r)
            pk[r] = (bf16)(o[dt][r] * rv);
        *(bf16x4*)&Pw[l15 * 72 + dt * 16 + quad * 4] = pk;
    }
#pragma unroll
    for (int i = 0; i < 2; ++i) {
        int row = i * 8 + (l >> 3);
        bf16x8 vv = *(const bf16x8*)&Pw[row * 72 + (l & 7) * 8];
        *(bf16x8*)(X + (size_t)(b * SEQ + qt16 * 16 + row) * DM + h * 64 + (l & 7) * 8) = vv;
    }
}

// ---------------- launcher ----------------
extern "C" void kernel_launch(void* const* d_in, const int* in_sizes, int n_in,
                              void* d_out, int out_size, void* d_ws, size_t ws_size,
                              hipStream_t stream) {
    const float* q  = (const float*)d_in[0];
    const float* k  = (const float*)d_in[1];
    const float* v  = (const float*)d_in[2];
    // d_in[3] = mask: causal tril, handled analytically
    const float* wq = (const float*)d_in[4];
    const float* bq = (const float*)d_in[5];
    const float* wk = (const float*)d_in[6];
    const float* bk = (const float*)d_in[7];
    const float* wv = (const float*)d_in[8];
    const float* bv = (const float*)d_in[9];
    const float* wo = (const float*)d_in[10];
    const float* bo = (const float*)d_in[11];
    float* out = (float*)d_out;

    uint8_t* ws = (uint8_t*)d_ws;
    const size_t SZ_ACT = (size_t)MROWS * DM * sizeof(bf16);  // 8 MB
    const size_t SZ_W   = (size_t)DM * DM * sizeof(bf16);     // 2 MB
    bf16* qb  = (bf16*)(ws);
    bf16* kb  = (bf16*)(ws + SZ_ACT);
    bf16* vb  = (bf16*)(ws + 2 * SZ_ACT);
    bf16* wqb = (bf16*)(ws + 3 * SZ_ACT);
    bf16* wkb = (bf16*)(ws + 3 * SZ_ACT + SZ_W);
    bf16* wvb = (bf16*)(ws + 3 * SZ_ACT + 2 * SZ_W);
    bf16* wob = (bf16*)(ws + 3 * SZ_ACT + 3 * SZ_W);
    bf16* Qf  = (bf16*)(ws + 3 * SZ_ACT + 4 * SZ_W);
    bf16* Kf  = (bf16*)(ws + 4 * SZ_ACT + 4 * SZ_W);
    bf16* Vf  = (bf16*)(ws + 5 * SZ_ACT + 4 * SZ_W);
    bf16* X   = (bf16*)(ws + 6 * SZ_ACT + 4 * SZ_W);
    // total: 7*SZ_ACT + 4*SZ_W = 64 MB

    // 1) convert to bf16
    {
        long total_vec4 = 3L * MROWS * DM / 4 + 4L * DM * DM / 4;
        k_convert<<<dim3((unsigned)(total_vec4 / 256)), 256, 0, stream>>>(
            q, k, v, wq, wk, wv, wo, qb, kb, vb, wqb, wkb, wvb, wob);
    }
    // 2) merged Q/K/V projections: 128x64 tiles, 1536 blocks = 6/CU
    k_gemm_qkv<<<dim3(512, 1, 3), 256, 0, stream>>>(
        qb, kb, vb, wqb, wkb, wvb, bq, bk, bv, Qf, Kf, Vf);
    // 3) causal flash attention (64-query blocks, dbuf K/V, 1 barrier/iter)
    k_flash<<<dim3(BATCH * NH, SEQ / 64), 256, 0, stream>>>(Qf, Kf, Vf, X);
    // 4) output projection -> fp32 (128x64 tiles, dbuf)
    k_gemm_out<<<dim3(DM / 64, MROWS / 128), 256, 0, stream>>>(X, wob, bo, out);
}

// Round 12
// 229.281 us; speedup vs baseline: 1.0690x; 1.0020x over previous
//
#include <hip/hip_runtime.h>
#include <hip/hip_bf16.h>
#include <cstdint>
#include <cstddef>

// ---- problem constants ----
#define BATCH 2
#define SEQ   2048
#define DM    1024
#define NH    16
#define DK    64
#define MROWS (BATCH*SEQ)   // 4096

typedef __bf16 bf16;
typedef float  f32x4  __attribute__((ext_vector_type(4)));
typedef bf16   bf16x8 __attribute__((ext_vector_type(8)));
typedef bf16   bf16x4 __attribute__((ext_vector_type(4)));

// verified (m89/m120): A[m=lane&15][k=(lane>>4)*8+j], B[n=lane&15][k=(lane>>4)*8+j],
// C/D: col(n)=lane&15, row(m)=(lane>>4)*4+reg
#define MFMA32(a, b, c) __builtin_amdgcn_mfma_f32_16x16x32_bf16(a, b, c, 0, 0, 0)

// async global->LDS, 16B per lane; LDS dest is wave-uniform base + lane*16
__device__ __forceinline__ void llds16(const void* gc, void* l) {
    void* g = (void*)gc;
    __builtin_amdgcn_global_load_lds(
        (__attribute__((address_space(1))) uint32_t*)g,
        (__attribute__((address_space(3))) uint32_t*)l,
        16, 0, 0);
}

// ---------------- fused fp32 -> bf16 convert (q,k,v + 4 weights) ----------------
__global__ __launch_bounds__(256) void k_convert(
    const float* __restrict__ q, const float* __restrict__ k, const float* __restrict__ v,
    const float* __restrict__ wq, const float* __restrict__ wk, const float* __restrict__ wv,
    const float* __restrict__ wo,
    bf16* __restrict__ qb, bf16* __restrict__ kb, bf16* __restrict__ vb,
    bf16* __restrict__ wqb, bf16* __restrict__ wkb, bf16* __restrict__ wvb,
    bf16* __restrict__ wob) {
    long t = (long)blockIdx.x * blockDim.x + threadIdx.x;   // one float4 per thread
    const long NQ = (long)MROWS * DM / 4;
    const long NW = (long)DM * DM / 4;
    const float* src; bf16* dst; long off;
    if (t < NQ)            { src = q;  dst = qb;  off = t; }
    else if (t < 2*NQ)     { src = k;  dst = kb;  off = t - NQ; }
    else if (t < 3*NQ)     { src = v;  dst = vb;  off = t - 2*NQ; }
    else {
        long u = t - 3*NQ;
        if (u < NW)        { src = wq; dst = wqb; off = u; }
        else if (u < 2*NW) { src = wk; dst = wkb; off = u - NW; }
        else if (u < 3*NW) { src = wv; dst = wvb; off = u - 2*NW; }
        else               { src = wo; dst = wob; off = u - 3*NW; }
    }
    f32x4 x = *(const f32x4*)(src + off * 4);
    bf16x4 y;
    y[0] = (bf16)x[0]; y[1] = (bf16)x[1]; y[2] = (bf16)x[2]; y[3] = (bf16)x[3];
    *(bf16x4*)(dst + off * 4) = y;
}

// ---- merged Q/K/V projections: 128(M)x64(N) tiles, 1536 blocks = 6/CU ----
// Static 2-barrier m97 staging, BK=32 (structural ~52us plateau; accepted).
// Qf/Kf entry (bh, s16 = s>>4, chunk = d>>5): lane l, elem e holds
//   [s-in-16 = l&15][d-in-32 = (l>>4)*8 + e]   (= MFMA A/B-operand order)
// Vf entry (bh, kc = s>>5, dtile = d>>4): PERMUTED k-slot order pi(quad*8+e) =
//   (e>>2)*16 + quad*4 + (e&3), so the flash P B-fragment needs NO lane exchange
//   (pb[e] = lane's own score E[2c+(e>>2)][e&3]). V A-frag and P B-frag agree on pi;
//   MFMA sums over k, so any consistent permutation is exact.
__global__ __launch_bounds__(256) void k_gemm_qkv(
    const bf16* __restrict__ qb, const bf16* __restrict__ kb, const bf16* __restrict__ vb,
    const bf16* __restrict__ wqb, const bf16* __restrict__ wkb, const bf16* __restrict__ wvb,
    const float* __restrict__ bq, const float* __restrict__ bk, const float* __restrict__ bv,
    bf16* __restrict__ Qf, bf16* __restrict__ Kf, bf16* __restrict__ Vf) {
    const int z = blockIdx.z;
    const int bid = blockIdx.x;
    const bf16* A; const bf16* B; const float* bias;
    int m0, n0;
    if (z == 2) {
        A = vb; B = wvb; bias = bv;
        m0 = (bid >> 4) * 128;        // s block (32 of them)
        n0 = (bid & 15) * 64;         // feature block (16)
    } else {
        A = z ? wkb : wqb; B = z ? kb : qb; bias = z ? bk : bq;
        m0 = (bid >> 6) * 128;        // feature block (8)
        n0 = (bid & 63) * 64;         // s block (64)
    }

    constexpr int K = DM, BK = 32;
    __shared__ bf16 sA[128 * BK];
    __shared__ bf16 sB[64 * BK];
    const int tid = threadIdx.x;
    const int l = tid & 63, w = tid >> 6;
    const int quad = l >> 4, l15 = l & 15;
    const int wm = w & 1, wn = w >> 1;
    const int srow = l >> 2, scol = (l & 3) * 8;

    f32x4 acc[4][2] = {};
    for (int k0 = 0; k0 < K; k0 += BK) {
#pragma unroll
        for (int i = 0; i < 2; ++i) {
            int r16 = w * 32 + i * 16;
            llds16(A + (size_t)(m0 + r16 + srow) * K + k0 + scol, &sA[r16 * BK]);
        }
        llds16(B + (size_t)(n0 + w * 16 + srow) * K + k0 + scol, &sB[w * 16 * BK]);
        __syncthreads();

        bf16x8 af[4], bfr[2];
#pragma unroll
        for (int mi = 0; mi < 4; ++mi)
            af[mi] = *(const bf16x8*)&sA[(wm * 64 + mi * 16 + l15) * BK + quad * 8];
#pragma unroll
        for (int ni = 0; ni < 2; ++ni)
            bfr[ni] = *(const bf16x8*)&sB[(wn * 32 + ni * 16 + l15) * BK + quad * 8];
#pragma unroll
        for (int mi = 0; mi < 4; ++mi)
#pragma unroll
            for (int ni = 0; ni < 2; ++ni)
                acc[mi][ni] = MFMA32(af[mi], bfr[ni], acc[mi][ni]);
        __syncthreads();
    }

    if (z == 2) {
        // V epilogue: acc element = V[s = m0+wm*64+mi*16+quad*4+r][d = n0+wn*32+ni*16+l15]
        // Store position per the permuted k-slot layout: lane = quad*16 + l15,
        // elem = (mi&1)*4 + r  (k32 = (mi&1)*16 + quad*4 + r -> slot (quad, (mi&1)*4+r))
#pragma unroll
        for (int ni = 0; ni < 2; ++ni) {
            int dcol = n0 + wn * 32 + ni * 16 + l15;
            int hh2 = dcol >> 6;                 // head
            int dtile = (dcol >> 4) & 3;         // (d&63)>>4
            float bias_v = bias[dcol];
#pragma unroll
            for (int mi = 0; mi < 4; ++mi) {
                int srw = m0 + wm * 64 + mi * 16;
                int bb = srw >> 11, sl = srw & 2047;
                int kc = sl >> 5;
                bf16x4 pack;
#pragma unroll
                for (int r = 0; r < 4; ++r)
                    pack[r] = (bf16)(acc[mi][ni][r] + bias_v);
                size_t entry = ((size_t)(bb * NH + hh2) * 64 + kc) * 4 + dtile;
                *(bf16x4*)(Vf + entry * 512 + (size_t)(quad * 16 + l15) * 8 + (mi & 1) * 4) = pack;
            }
        }
    } else {
        // Q/K epilogue: acc element = D[feature = m0+wm*64+mi*16+quad*4+r][s = n0+wn*32+ni*16+l15]
        bf16* out = z ? Kf : Qf;
        const float scale = z ? 1.0f : 0.18033688f;   // Q carries 0.125 * log2(e)
        float bias_rv[4][4];
#pragma unroll
        for (int mi = 0; mi < 4; ++mi)
#pragma unroll
            for (int r = 0; r < 4; ++r)
                bias_rv[mi][r] = bias[m0 + wm * 64 + mi * 16 + quad * 4 + r];
#pragma unroll
        for (int ni = 0; ni < 2; ++ni) {
            int scolg = n0 + wn * 32 + ni * 16 + l15;
            int bb = scolg >> 11, s = scolg & 2047;
            int s16 = s >> 4;
#pragma unroll
            for (int mi = 0; mi < 4; ++mi) {
                int drow = m0 + wm * 64 + mi * 16;
                int hh2 = (drow >> 6) & 15;
                int chunk = (drow & 63) >> 5;
                int qp = 2 * (mi & 1) + (quad >> 1);   // (d32)>>3
                bf16x4 pack;
#pragma unroll
                for (int r = 0; r < 4; ++r)
                    pack[r] = (bf16)((acc[mi][ni][r] + bias_rv[mi][r]) * scale);
                size_t entry = ((size_t)(bb * NH + hh2) * 128 + s16) * 2 + chunk;
                *(bf16x4*)(out + entry * 512 + (size_t)(qp * 16 + l15) * 8 + (quad & 1) * 4) = pack;
            }
        }
    }
}

// ---- output projection: 128(M)x64(N) tiles, m97 staging, dbuf, 1 barrier/k-step ----
__global__ __launch_bounds__(256) void k_gemm_out(
    const bf16* __restrict__ X, const bf16* __restrict__ wob,
    const float* __restrict__ bo, float* __restrict__ out) {
    constexpr int K = DM, BK = 32, NS = K / BK;
    const int m0 = blockIdx.y * 128, n0 = blockIdx.x * 64;
    __shared__ bf16 sA[2][128 * BK];
    __shared__ bf16 sB[2][64 * BK];
    const int tid = threadIdx.x;
    const int l = tid & 63, w = tid >> 6;
    const int quad = l >> 4, l15 = l & 15;
    const int wm = w & 1, wn = w >> 1;
    const int srow = l >> 2, scol = (l & 3) * 8;

#pragma unroll
    for (int i = 0; i < 2; ++i) {
        int r16 = w * 32 + i * 16;
        llds16(X + (size_t)(m0 + r16 + srow) * K + scol, &sA[0][r16 * BK]);
    }
    llds16(wob + (size_t)(n0 + w * 16 + srow) * K + scol, &sB[0][w * 16 * BK]);

    f32x4 acc[4][2] = {};
    for (int s = 0; s < NS; ++s) {
        __syncthreads();
        const int cur = s & 1;
        if (s + 1 < NS) {
            const int k0 = (s + 1) * BK;
#pragma unroll
            for (int i = 0; i < 2; ++i) {
                int r16 = w * 32 + i * 16;
                llds16(X + (size_t)(m0 + r16 + srow) * K + k0 + scol, &sA[cur ^ 1][r16 * BK]);
            }
            llds16(wob + (size_t)(n0 + w * 16 + srow) * K + k0 + scol, &sB[cur ^ 1][w * 16 * BK]);
        }

        bf16x8 af[4], bfr[2];
#pragma unroll
        for (int mi = 0; mi < 4; ++mi)
            af[mi] = *(const bf16x8*)&sA[cur][(wm * 64 + mi * 16 + l15) * BK + quad * 8];
#pragma unroll
        for (int ni = 0; ni < 2; ++ni)
            bfr[ni] = *(const bf16x8*)&sB[cur][(wn * 32 + ni * 16 + l15) * BK + quad * 8];
#pragma unroll
        for (int mi = 0; mi < 4; ++mi)
#pragma unroll
            for (int ni = 0; ni < 2; ++ni)
                acc[mi][ni] = MFMA32(af[mi], bfr[ni], acc[mi][ni]);
    }
#pragma unroll
    for (int mi = 0; mi < 4; ++mi)
#pragma unroll
        for (int ni = 0; ni < 2; ++ni) {
            int col = n0 + wn * 32 + ni * 16 + l15;
            float bias_v = bo[col];
            int rbase = m0 + wm * 64 + mi * 16 + quad * 4;
#pragma unroll
            for (int r = 0; r < 4; ++r)
                out[(size_t)(rbase + r) * DM + col] = acc[mi][ni][r] + bias_v;
        }
}

// ---------------- causal flash attention: P stays in registers (zero-shuffle) ----------------
// grid (bh=32, 32): qt = 31 - y (LPT); XCD = linear_id&7 = bh&7 pins each bh's K/V.
// Block = 256 thr = 4 waves on one 64-query tile. K/V j-tile (16 entries, 16KB)
// double-buffered, ONE barrier per iter. S^T = K·Q^T keeps query = l15 in-lane.
// PV uses the permuted Vf k-slot layout so the P B-fragment is the lane's own
// score registers: pb[e] = E[2c+(e>>2)][e&3] -- no LDS round-trip, no shuffles.
// LDS traffic/wave-j: 26KB -> 16KB (was the flash bottleneck); LDS 41 -> 32KB.
__global__ __launch_bounds__(256, 4) void k_flash(const bf16* __restrict__ Qf,
                                                  const bf16* __restrict__ Kf,
                                                  const bf16* __restrict__ Vf,
                                                  bf16* __restrict__ X) {
    const int bh = blockIdx.x;
    const int qt = 31 - (int)blockIdx.y;      // LPT order
    const int b = bh >> 4, h = bh & 15;
    const int tid = threadIdx.x, w = tid >> 6, l = tid & 63;
    const int quad = l >> 4, l15 = l & 15;
    __shared__ bf16 sKV[2][16 * 512];         // [buf][e]: e 0..7 = K (ni*2+c), 8..15 = V (8+c*4+dt)

    const bf16* qfp = Qf + (size_t)bh * 128 * 1024;
    const bf16* kfp = Kf + (size_t)bh * 128 * 1024;
    const bf16* vfp = Vf + (size_t)bh * 64 * 4 * 512;

    const int qt16 = qt * 4 + w;              // wave's 16-query tile (s16 index)
    const int qglob = qt16 * 16 + l15;

    // persistent Q B-frags (d 0..31, 32..63)
    bf16x8 qf[2];
#pragma unroll
    for (int c = 0; c < 2; ++c)
        qf[c] = *(const bf16x8*)(qfp + ((size_t)qt16 * 2 + c) * 512 + (size_t)l * 8);

    f32x4 o[4] = {};            // O^T: row = d-in-16 (per dtile), col = query = l15
    float lp = 0.f;             // per-lane partial softmax denom

    // preload tile 0: wave w stages entries w*4..w*4+3
#pragma unroll
    for (int i = 0; i < 4; ++i) {
        int e = w * 4 + i;
        const bf16* src = (e < 8) ? kfp + ((size_t)e) * 512
                                  : vfp + ((size_t)(e - 8)) * 512;
        llds16(src + (size_t)l * 8, &sKV[0][e * 512]);
    }

    for (int j = 0; j <= qt; ++j) {
        __syncthreads();        // staging of tile j (issued last iter) now visible
        const bf16* cur = sKV[j & 1];
        if (j < qt) {
            int j1 = j + 1;
#pragma unroll
            for (int i = 0; i < 4; ++i) {
                int e = w * 4 + i;
                const bf16* src = (e < 8) ? kfp + ((size_t)(j1 * 8 + e)) * 512
                                          : vfp + ((size_t)(j1 * 8 + (e - 8))) * 512;
                llds16(src + (size_t)l * 8, (void*)&sKV[j1 & 1][e * 512]);
            }
        }

        // ---- S^T = K·Q^T per 16-key subtile (frags from LDS, stride-1) ----
        f32x4 st[4];
#pragma unroll
        for (int ni = 0; ni < 4; ++ni) {
            bf16x8 k0 = *(const bf16x8*)&cur[(size_t)(ni * 2 + 0) * 512 + l * 8];
            bf16x8 k1 = *(const bf16x8*)&cur[(size_t)(ni * 2 + 1) * 512 + l * 8];
            f32x4 zz = {};
            zz = MFMA32(k0, qf[0], zz);
            st[ni] = MFMA32(k1, qf[1], zz);
        }

        // ---- fixed-m softmax (log2 domain) + in-register P + PV per 32-key chunk ----
        const bool diag = (j == qt);
#pragma unroll
        for (int c = 0; c < 2; ++c) {
            bf16x8 pb;
#pragma unroll
            for (int half = 0; half < 2; ++half) {
                int ni = 2 * c + half;
#pragma unroll
                for (int r = 0; r < 4; ++r) {
                    float s = st[ni][r];
                    if (diag) {
                        int key = j * 64 + ni * 16 + quad * 4 + r;
                        if (key > qglob) s = -1e30f;
                    }
                    float e = __builtin_amdgcn_exp2f(s);
                    lp += e;
                    pb[half * 4 + r] = (bf16)e;
                }
            }
#pragma unroll
            for (int dt = 0; dt < 4; ++dt) {
                bf16x8 vv = *(const bf16x8*)&cur[(size_t)(8 + c * 4 + dt) * 512 + l * 8];
                o[dt] = MFMA32(vv, pb, o[dt]);
            }
        }
    }

    // ---- reduce denom across quads (queries are per-lane) ----
    lp += __shfl_xor(lp, 16, 64);
    lp += __shfl_xor(lp, 32, 64);
    float rv = 1.f / lp;

    // ---- normalize, repack via LDS (reuse sKV after barrier), coalesced store ----
    __syncthreads();            // all waves done reading sKV
    bf16* Xw = &sKV[0][w * 16 * 72];   // wave-private repack region (4 x 2304 B)
#pragma unroll
    for (int dt = 0; dt < 4; ++dt) {
        bf16x4 pk;
#pragma unroll
        for (int r = 0; r < 4; ++r)
            pk[r] = (bf16)(o[dt][r] * rv);
        *(bf16x4*)&Xw[l15 * 72 + dt * 16 + quad * 4] = pk;
    }
#pragma unroll
    for (int i = 0; i < 2; ++i) {
        int row = i * 8 + (l >> 3);
        bf16x8 vv = *(const bf16x8*)&Xw[row * 72 + (l & 7) * 8];
        *(bf16x8*)(X + (size_t)(b * SEQ + qt16 * 16 + row) * DM + h * 64 + (l & 7) * 8) = vv;
    }
}

// ---------------- launcher ----------------
extern "C" void kernel_launch(void* const* d_in, const int* in_sizes, int n_in,
                              void* d_out, int out_size, void* d_ws, size_t ws_size,
                              hipStream_t stream) {
    const float* q  = (const float*)d_in[0];
    const float* k  = (const float*)d_in[1];
    const float* v  = (const float*)d_in[2];
    // d_in[3] = mask: causal tril, handled analytically
    const float* wq = (const float*)d_in[4];
    const float* bq = (const float*)d_in[5];
    const float* wk = (const float*)d_in[6];
    const float* bk = (const float*)d_in[7];
    const float* wv = (const float*)d_in[8];
    const float* bv = (const float*)d_in[9];
    const float* wo = (const float*)d_in[10];
    const float* bo = (const float*)d_in[11];
    float* out = (float*)d_out;

    uint8_t* ws = (uint8_t*)d_ws;
    const size_t SZ_ACT = (size_t)MROWS * DM * sizeof(bf16);  // 8 MB
    const size_t SZ_W   = (size_t)DM * DM * sizeof(bf16);     // 2 MB
    bf16* qb  = (bf16*)(ws);
    bf16* kb  = (bf16*)(ws + SZ_ACT);
    bf16* vb  = (bf16*)(ws + 2 * SZ_ACT);
    bf16* wqb = (bf16*)(ws + 3 * SZ_ACT);
    bf16* wkb = (bf16*)(ws + 3 * SZ_ACT + SZ_W);
    bf16* wvb = (bf16*)(ws + 3 * SZ_ACT + 2 * SZ_W);
    bf16* wob = (bf16*)(ws + 3 * SZ_ACT + 3 * SZ_W);
    bf16* Qf  = (bf16*)(ws + 3 * SZ_ACT + 4 * SZ_W);
    bf16* Kf  = (bf16*)(ws + 4 * SZ_ACT + 4 * SZ_W);
    bf16* Vf  = (bf16*)(ws + 5 * SZ_ACT + 4 * SZ_W);
    bf16* X   = (bf16*)(ws + 6 * SZ_ACT + 4 * SZ_W);
    // total: 7*SZ_ACT + 4*SZ_W = 64 MB

    // 1) convert to bf16
    {
        long total_vec4 = 3L * MROWS * DM / 4 + 4L * DM * DM / 4;
        k_convert<<<dim3((unsigned)(total_vec4 / 256)), 256, 0, stream>>>(
            q, k, v, wq, wk, wv, wo, qb, kb, vb, wqb, wkb, wvb, wob);
    }
    // 2) merged Q/K/V projections: 128x64 tiles, 1536 blocks = 6/CU
    k_gemm_qkv<<<dim3(512, 1, 3), 256, 0, stream>>>(
        qb, kb, vb, wqb, wkb, wvb, bq, bk, bv, Qf, Kf, Vf);
    // 3) causal flash attention (64-query blocks, dbuf K/V, in-register P)
    k_flash<<<dim3(BATCH * NH, SEQ / 64), 256, 0, stream>>>(Qf, Kf, Vf, X);
    // 4) output projection -> fp32 (128x64 tiles, dbuf)
    k_gemm_out<<<dim3(DM / 64, MROWS / 128), 256, 0, stream>>>(X, wob, bo, out);
}